// Round 1
// baseline (258.739 us; speedup 1.0000x reference)
//
#include <hip/hip_runtime.h>
#include <hip/hip_bf16.h>
#include <math.h>
#include <stdint.h>

// Disable FP contraction everywhere: tie-breaking in GT matching (quality =
// 1e8 - area, ulp=8 at 1e8) and decode must bit-match a mul-then-round
// numpy reference. FMA contraction would silently change argmax winners.
#pragma clang fp contract(off)

#define NB   16
#define NC   20
#define NM   64
#define NT   21504
#define OFF1 16384
#define OFF2 20480
#define TOPK 1000
#define DELTA_OFF 80000L
#define CTR_OFF   1456256L

// ---------- dtype-dispatched load/store (flag: 0 = float32, 1 = bf16) ----------
__device__ __forceinline__ float ldin(const void* p, long i, int bf) {
  if (bf) {
    unsigned w = ((unsigned)((const unsigned short*)p)[i]) << 16;
    return __uint_as_float(w);
  }
  return ((const float*)p)[i];
}
__device__ __forceinline__ void stout(void* p, long i, float v, int bf) {
  if (bf) {
    unsigned w = __float_as_uint(v);
    unsigned r = (w + 0x7FFFu + ((w >> 16) & 1u)) >> 16;  // RNE
    ((unsigned short*)p)[i] = (unsigned short)r;
  } else {
    ((float*)p)[i] = v;
  }
}

// ---------- K0: detect input dtype from locs_p3[0] == 4.0 ----------
__global__ void k_flag(const void* locs0, int* flag) {
  unsigned w = ((const unsigned*)locs0)[0];
  // float32 4.0f = 0x40800000 (low 16 bits zero); bf16 pair = 0x40804080
  *flag = ((w & 0xFFFFu) == 0u) ? 0 : 1;
}

// ---------- K1: GT matching -> gt_deltas, gt_ctr ----------
__global__ void k_targets(const void* locs0, const void* locs1, const void* locs2,
                          const void* gt, void* out, const int* flagp) {
  __shared__ float sgt[NM * 5];
  const int bf = *flagp;
  const int b  = blockIdx.y;
  const int n  = blockIdx.x * blockDim.x + threadIdx.x;
  for (int i = threadIdx.x; i < NM * 5; i += blockDim.x)
    sgt[i] = ldin(gt, (long)b * NM * 5 + i, bf);
  __syncthreads();
  if (n >= NT) return;

  const void* L; int nl; float stride, lower, upper;
  if (n < OFF1)      { L = locs0; nl = n;        stride = 8.f;  lower = 0.f;   upper = 64.f; }
  else if (n < OFF2) { L = locs1; nl = n - OFF1; stride = 16.f; lower = 64.f;  upper = 128.f; }
  else               { L = locs2; nl = n - OFF2; stride = 32.f; lower = 128.f; upper = INFINITY; }

  float cx = ldin(L, (long)nl * 2 + 0, bf);
  float cy = ldin(L, (long)nl * 2 + 1, bf);

  float best = -1.0f; int bi = 0;            // argmax-first semantics (strict >)
  for (int m = 0; m < NM; ++m) {
    float g0 = sgt[m*5+0], g1 = sgt[m*5+1], g2 = sgt[m*5+2], g3 = sgt[m*5+3];
    float l = cx - g0, t = cy - g1, r = g2 - cx, d = g3 - cy;
    float mn = fminf(fminf(l, t), fminf(r, d));
    float mx = fmaxf(fmaxf(l, t), fmaxf(r, d));
    bool  ok = (mn > 0.f) && (mx > lower) && (mx < upper);
    float area = (g2 - g0) * (g3 - g1);
    float q = ok ? (100000000.0f - area) : 0.f;
    if (q > best) { best = q; bi = m; }
  }

  float d0, d1, d2, d3, ctrv;
  if (best < 1e-5f) {
    d0 = d1 = d2 = d3 = -1.f; ctrv = -1.f;
  } else {
    float m0 = sgt[bi*5+0], m1 = sgt[bi*5+1], m2 = sgt[bi*5+2], m3 = sgt[bi*5+3];
    d0 = (cx - m0) / stride; d1 = (cy - m1) / stride;
    d2 = (m2 - cx) / stride; d3 = (m3 - cy) / stride;
    float mnlr = fminf(d0, d2), mntb = fminf(d1, d3);
    float mxlr = fmaxf(d0, d2), mxtb = fmaxf(d1, d3);
    ctrv = sqrtf((mnlr * mntb) / (mxlr * mxtb));
  }
  long base = DELTA_OFF + ((long)b * NT + n) * 4;
  stout(out, base + 0, d0, bf);
  stout(out, base + 1, d1, bf);
  stout(out, base + 2, d2, bf);
  stout(out, base + 3, d3, bf);
  stout(out, CTR_OFF + (long)b * NT + n, ctrv, bf);
}

// ---------- K2: scores + decode -> ws ----------
__global__ void k_scores(const void* locs0, const void* locs1, const void* locs2,
                         const void* cls0, const void* cls1, const void* cls2,
                         const void* reg0, const void* reg1, const void* reg2,
                         const void* ctr0, const void* ctr1, const void* ctr2,
                         float* scores, float* boxesw, float* cidw, const int* flagp) {
  const int bf = *flagp;
  const int b  = blockIdx.y;
  const int n  = blockIdx.x * blockDim.x + threadIdx.x;
  if (n >= NT) return;

  const void *L, *CL, *RG, *CT; int nl, NL; float stride;
  if (n < OFF1)      { L=locs0; CL=cls0; RG=reg0; CT=ctr0; nl=n;        NL=16384; stride=8.f; }
  else if (n < OFF2) { L=locs1; CL=cls1; RG=reg1; CT=ctr1; nl=n-OFF1;   NL=4096;  stride=16.f; }
  else               { L=locs2; CL=cls2; RG=reg2; CT=ctr2; nl=n-OFF2;   NL=1024;  stride=32.f; }

  float ct  = ldin(CT, (long)b * NL + nl, bf);
  float sct = 1.0f / (1.0f + expf(-ct));

  long cbase = ((long)b * NL + nl) * NC;
  float smax = -1.0f; int ci = 0;            // argmax over sqrt-scores, strict >
  for (int c = 0; c < NC; ++c) {
    float v = ldin(CL, cbase + c, bf);
    float sv = 1.0f / (1.0f + expf(-v));
    float s  = sqrtf(sv * sct);
    if (s > smax) { smax = s; ci = c; }
  }

  long rbase = ((long)b * NL + nl) * 4;
  float r0 = fmaxf(ldin(RG, rbase + 0, bf), 0.f);
  float r1 = fmaxf(ldin(RG, rbase + 1, bf), 0.f);
  float r2 = fmaxf(ldin(RG, rbase + 2, bf), 0.f);
  float r3 = fmaxf(ldin(RG, rbase + 3, bf), 0.f);
  float cx = ldin(L, (long)nl * 2 + 0, bf);
  float cy = ldin(L, (long)nl * 2 + 1, bf);

  long o = (long)b * NT + n;
  scores[o]       = smax;
  boxesw[o*4 + 0] = cx - r0 * stride;
  boxesw[o*4 + 1] = cy - r1 * stride;
  boxesw[o*4 + 2] = cx + r2 * stride;
  boxesw[o*4 + 3] = cy + r3 * stride;
  cidw[o]         = (float)ci;
}

// ---------- K3: exact top-1000 (radix select + bitonic) + greedy NMS + dets ----------
__global__ __launch_bounds__(1024)
void k_topk_nms(const float* scores, const float* boxesw, const float* cidw,
                void* out, const int* flagp) {
  const int bf  = *flagp;
  const int b   = blockIdx.x;
  const int tid = threadIdx.x;
  const float* sb = scores + (long)b * NT;

  __shared__ unsigned hist[256];
  __shared__ unsigned sPrefix, sRemaining, selCnt;
  __shared__ unsigned long long selKeys[1024];
  __shared__ float bxs[TOPK * 4];
  __shared__ float sbx[TOPK * 4];       // also reused as reduction buffer
  __shared__ float areaS[TOPK];
  __shared__ float scS[TOPK];
  __shared__ float cidS[TOPK];
  __shared__ int   suppS[TOPK];
  __shared__ unsigned char keepS[TOPK];
  __shared__ float sMaxC;

  // --- radix select: find V = 1000th smallest inv-key (inv = ~bits(score)) ---
  if (tid == 0) { sPrefix = 0u; sRemaining = TOPK; }
  __syncthreads();
  for (int shift = 24; shift >= 0; shift -= 8) {
    if (tid < 256) hist[tid] = 0u;
    __syncthreads();
    unsigned pref   = sPrefix;
    unsigned hiMask = (shift == 24) ? 0u : (0xFFFFFFFFu << (shift + 8));
    for (int i = tid; i < NT; i += 1024) {
      unsigned inv = ~__float_as_uint(sb[i]);
      if ((inv & hiMask) == (pref & hiMask))
        atomicAdd(&hist[(inv >> shift) & 0xFFu], 1u);
    }
    __syncthreads();
    if (tid == 0) {
      unsigned rem = sRemaining, cum = 0u; int v = 0;
      for (; v < 256; ++v) { unsigned h = hist[v]; if (cum + h >= rem) break; cum += h; }
      sPrefix    = pref | ((unsigned)v << shift);
      sRemaining = rem - cum;
    }
    __syncthreads();
  }
  const unsigned V = sPrefix;

  // --- gather candidates: all inv < V first (<=999), then ties at V ---
  if (tid == 0) selCnt = 0u;
  __syncthreads();
  for (int i = tid; i < NT; i += 1024) {
    unsigned inv = ~__float_as_uint(sb[i]);
    if (inv < V) {
      unsigned p = atomicAdd(&selCnt, 1u);
      if (p < 1024u) selKeys[p] = ((unsigned long long)inv << 32) | (unsigned)i;
    }
  }
  __syncthreads();
  for (int i = tid; i < NT; i += 1024) {
    unsigned inv = ~__float_as_uint(sb[i]);
    if (inv == V) {
      unsigned p = atomicAdd(&selCnt, 1u);
      if (p < 1024u) selKeys[p] = ((unsigned long long)inv << 32) | (unsigned)i;
    }
  }
  __syncthreads();
  unsigned total = selCnt < 1024u ? selCnt : 1024u;
  if ((unsigned)tid >= total) selKeys[tid] = 0xFFFFFFFFFFFFFFFFull;
  __syncthreads();

  // --- bitonic sort ascending (score desc, idx asc) ---
  for (unsigned k = 2; k <= 1024; k <<= 1) {
    for (unsigned j = k >> 1; j > 0; j >>= 1) {
      unsigned ixj = (unsigned)tid ^ j;
      if (ixj > (unsigned)tid) {
        unsigned long long a = selKeys[tid], c = selKeys[ixj];
        bool up = ((tid & k) == 0);
        if (up ? (a > c) : (a < c)) { selKeys[tid] = c; selKeys[ixj] = a; }
      }
      __syncthreads();
    }
  }

  // --- gather top-1000 boxes/scores/cls ---
  if (tid < TOPK) {
    unsigned long long key = selKeys[tid];
    unsigned idx = (unsigned)(key & 0xFFFFFFFFull);
    unsigned inv = (unsigned)(key >> 32);
    scS[tid] = __uint_as_float(~inv);
    long o = (long)b * NT + idx;
    bxs[tid*4+0] = boxesw[o*4+0];
    bxs[tid*4+1] = boxesw[o*4+1];
    bxs[tid*4+2] = boxesw[o*4+2];
    bxs[tid*4+3] = boxesw[o*4+3];
    cidS[tid] = cidw[o];
    suppS[tid] = 0;
    keepS[tid] = 0;
  }
  __syncthreads();

  // --- max_coord = max(where(valid, bx, 0)) ---
  float* red = sbx;  // reuse before sbx is written
  float loc = -INFINITY;
  if (tid < TOPK)
    loc = (scS[tid] > 0.3f)
            ? fmaxf(fmaxf(bxs[tid*4+0], bxs[tid*4+1]), fmaxf(bxs[tid*4+2], bxs[tid*4+3]))
            : 0.0f;
  red[tid] = loc;
  __syncthreads();
  for (int s = 512; s > 0; s >>= 1) {
    if (tid < s) red[tid] = fmaxf(red[tid], red[tid + s]);
    __syncthreads();
  }
  if (tid == 0) sMaxC = red[0];
  __syncthreads();

  // --- shifted boxes + areas (computed from shifted coords, like the ref) ---
  float offm = sMaxC + 1.0f;
  if (tid < TOPK) {
    float o4 = cidS[tid] * offm;
    float s0 = bxs[tid*4+0] + o4;
    float s1 = bxs[tid*4+1] + o4;
    float s2 = bxs[tid*4+2] + o4;
    float s3 = bxs[tid*4+3] + o4;
    sbx[tid*4+0] = s0; sbx[tid*4+1] = s1; sbx[tid*4+2] = s2; sbx[tid*4+3] = s3;
    areaS[tid] = (s2 - s0) * (s3 - s1);
  }
  __syncthreads();

  // --- greedy NMS (== 100 iterations of argmax-of-active on sorted scores) ---
  int kept = 0;
  for (int i = 0; i < TOPK; ++i) {
    bool ok = (suppS[i] == 0) && (scS[i] > 0.3f);   // uniform across block
    if (ok) {
      if (tid == 0) keepS[i] = 1;
      float b0 = sbx[i*4+0], b1 = sbx[i*4+1], b2 = sbx[i*4+2], b3 = sbx[i*4+3];
      float ai = areaS[i];
      if (tid < TOPK) {
        float xx1 = fmaxf(b0, sbx[tid*4+0]);
        float yy1 = fmaxf(b1, sbx[tid*4+1]);
        float xx2 = fminf(b2, sbx[tid*4+2]);
        float yy2 = fminf(b3, sbx[tid*4+3]);
        float inter = fmaxf(xx2 - xx1, 0.f) * fmaxf(yy2 - yy1, 0.f);
        float iou = inter / (ai + areaS[tid] - inter);
        if (!(iou <= 0.5f)) suppS[tid] = 1;   // NaN suppresses, like the ref
      }
      __syncthreads();
      if (++kept >= 100) break;
    }
  }
  __syncthreads();

  // --- write dets ---
  if (tid < TOPK) {
    long o = ((long)b * TOPK + tid) * 5;
    if (keepS[tid]) {
      stout(out, o + 0, bxs[tid*4+0], bf);
      stout(out, o + 1, bxs[tid*4+1], bf);
      stout(out, o + 2, bxs[tid*4+2], bf);
      stout(out, o + 3, bxs[tid*4+3], bf);
      stout(out, o + 4, scS[tid],     bf);
    } else {
      stout(out, o + 0, 0.f, bf); stout(out, o + 1, 0.f, bf);
      stout(out, o + 2, 0.f, bf); stout(out, o + 3, 0.f, bf);
      stout(out, o + 4, 0.f, bf);
    }
  }
}

extern "C" void kernel_launch(void* const* d_in, const int* in_sizes, int n_in,
                              void* d_out, int out_size, void* d_ws, size_t ws_size,
                              hipStream_t stream) {
  const void* locs0 = d_in[0];
  const void* locs1 = d_in[1];
  const void* locs2 = d_in[2];
  const void* gt    = d_in[3];

  // Input order: dict order (cls_p3,reg_p3,ctr_p3, cls_p4,...) vs signature
  // order (cls_p3,cls_p4,cls_p5, reg_p3,...). Discriminate via in_sizes[5]:
  // dict -> reg_p3 = 16*16384*4 = 1048576; signature -> cls_p4 = 1310720.
  int ic[3], ir[3], it[3];
  if (n_in >= 13 && in_sizes[5] == 16 * 4096 * 20) {
    ic[0]=4; ic[1]=5; ic[2]=6;  ir[0]=7; ir[1]=8; ir[2]=9;  it[0]=10; it[1]=11; it[2]=12;
  } else {
    ic[0]=4; ic[1]=7; ic[2]=10; ir[0]=5; ir[1]=8; ir[2]=11; it[0]=6;  it[1]=9;  it[2]=12;
  }
  const void* cls0 = d_in[ic[0]]; const void* cls1 = d_in[ic[1]]; const void* cls2 = d_in[ic[2]];
  const void* reg0 = d_in[ir[0]]; const void* reg1 = d_in[ir[1]]; const void* reg2 = d_in[ir[2]];
  const void* ctr0 = d_in[it[0]]; const void* ctr1 = d_in[it[1]]; const void* ctr2 = d_in[it[2]];

  // workspace layout
  char* ws = (char*)d_ws;
  int*   flag   = (int*)ws;
  float* scores = (float*)(ws + 16);
  float* boxesw = scores + (long)NB * NT;        // 16*21504 floats
  float* cidw   = boxesw + (long)NB * NT * 4;    // +16*21504*4 floats

  dim3 grid(NT / 256, NB);

  k_flag<<<1, 1, 0, stream>>>(locs0, flag);
  k_targets<<<grid, 256, 0, stream>>>(locs0, locs1, locs2, gt, d_out, flag);
  k_scores<<<grid, 256, 0, stream>>>(locs0, locs1, locs2,
                                     cls0, cls1, cls2,
                                     reg0, reg1, reg2,
                                     ctr0, ctr1, ctr2,
                                     scores, boxesw, cidw, flag);
  k_topk_nms<<<NB, 1024, 0, stream>>>(scores, boxesw, cidw, d_out, flag);
}

// Round 2
// 218.359 us; speedup vs baseline: 1.1849x; 1.1849x over previous
//
#include <hip/hip_runtime.h>
#include <hip/hip_bf16.h>
#include <math.h>
#include <stdint.h>

// Disable FP contraction: tie-breaking (quality = 1e8 - area, ulp=8 at 1e8)
// and decode must bit-match the mul-then-round numpy reference.
#pragma clang fp contract(off)

#define NB   16
#define NC   20
#define NM   64
#define NT   21504
#define OFF1 16384
#define OFF2 20480
#define TOPK 1000
#define DELTA_OFF 80000L
#define CTR_OFF   1456256L

// ---------- dtype-dispatched load/store (flag: 0 = float32, 1 = bf16) ----------
__device__ __forceinline__ float ldin(const void* p, long i, int bf) {
  if (bf) return __uint_as_float(((unsigned)((const unsigned short*)p)[i]) << 16);
  return ((const float*)p)[i];
}
__device__ __forceinline__ unsigned short f2bf(float v) {
  unsigned w = __float_as_uint(v);
  return (unsigned short)((w + 0x7FFFu + ((w >> 16) & 1u)) >> 16);  // RNE
}
__device__ __forceinline__ void stout(void* p, long i, float v, int bf) {
  if (bf) ((unsigned short*)p)[i] = f2bf(v);
  else    ((float*)p)[i] = v;
}

// ---------- K0: detect input dtype from locs_p3[0] == 4.0 ----------
__global__ void k_flag(const void* locs0, int* flag) {
  unsigned w = ((const unsigned*)locs0)[0];
  *flag = ((w & 0xFFFFu) == 0u) ? 0 : 1;  // f32 4.0 = 0x40800000
}

// ---------- K1: fused targets + scores/decode ----------
__global__ __launch_bounds__(256)
void k_main(const void* locs0, const void* locs1, const void* locs2,
            const void* gt,
            const void* cls0, const void* cls1, const void* cls2,
            const void* reg0, const void* reg1, const void* reg2,
            const void* ctr0, const void* ctr1, const void* ctr2,
            void* out, float* scores, float* boxesw, float* cidw,
            const int* flagp) {
  __shared__ float sgt[NM * 5];
  __shared__ float scls[256 * 21];   // 256 locations x 20 classes, pad stride 21
  const int bf  = *flagp;
  const int b   = blockIdx.y;
  const int blk = blockIdx.x;
  const int tid = threadIdx.x;
  const int n   = blk * 256 + tid;

  const void *L, *CL, *RG, *CT; int NL, base; float stride, lower, upper;
  if (blk < 64)      { L=locs0; CL=cls0; RG=reg0; CT=ctr0; NL=16384; base=0;    stride=8.f;  lower=0.f;   upper=64.f; }
  else if (blk < 80) { L=locs1; CL=cls1; RG=reg1; CT=ctr1; NL=4096;  base=OFF1; stride=16.f; lower=64.f;  upper=128.f; }
  else               { L=locs2; CL=cls2; RG=reg2; CT=ctr2; NL=1024;  base=OFF2; stride=32.f; lower=128.f; upper=INFINITY; }
  const int nl     = n - base;
  const int nlBase = blk * 256 - base;

  for (int i = tid; i < NM * 5; i += 256) sgt[i] = ldin(gt, (long)b * NM * 5 + i, bf);

  // stage cls tile coalesced
  long cbase = ((long)b * NL + nlBase) * NC;   // divisible by 4 (NC=20)
  if (!bf) {
    const float4* p = (const float4*)((const float*)CL + cbase);
    for (int i = tid; i < 1280; i += 256) {
      float4 v = p[i];
      int e = i * 4;
      scls[( e      / 20) * 21 +  e      % 20] = v.x;
      scls[((e + 1) / 20) * 21 + (e + 1) % 20] = v.y;
      scls[((e + 2) / 20) * 21 + (e + 2) % 20] = v.z;
      scls[((e + 3) / 20) * 21 + (e + 3) % 20] = v.w;
    }
  } else {
    const unsigned* p = (const unsigned*)((const unsigned short*)CL + cbase);
    for (int i = tid; i < 2560; i += 256) {
      unsigned w = p[i];
      int e = i * 2;
      scls[( e      / 20) * 21 +  e      % 20] = __uint_as_float((w & 0xFFFFu) << 16);
      scls[((e + 1) / 20) * 21 + (e + 1) % 20] = __uint_as_float(w & 0xFFFF0000u);
    }
  }
  __syncthreads();

  float cx = ldin(L, (long)nl * 2 + 0, bf);
  float cy = ldin(L, (long)nl * 2 + 1, bf);

  // ---- GT matching / targets ----
  float best = -1.0f; int bi = 0;              // argmax-first (strict >)
  for (int m = 0; m < NM; ++m) {
    float g0 = sgt[m*5+0], g1 = sgt[m*5+1], g2 = sgt[m*5+2], g3 = sgt[m*5+3];
    float l = cx - g0, t = cy - g1, r = g2 - cx, d = g3 - cy;
    float mn = fminf(fminf(l, t), fminf(r, d));
    float mx = fmaxf(fmaxf(l, t), fmaxf(r, d));
    bool  ok = (mn > 0.f) && (mx > lower) && (mx < upper);
    float area = (g2 - g0) * (g3 - g1);
    float q = ok ? (100000000.0f - area) : 0.f;
    if (q > best) { best = q; bi = m; }
  }
  float d0, d1, d2, d3, ctrv;
  if (best < 1e-5f) {
    d0 = d1 = d2 = d3 = -1.f; ctrv = -1.f;
  } else {
    float m0 = sgt[bi*5+0], m1 = sgt[bi*5+1], m2 = sgt[bi*5+2], m3 = sgt[bi*5+3];
    d0 = (cx - m0) / stride; d1 = (cy - m1) / stride;
    d2 = (m2 - cx) / stride; d3 = (m3 - cy) / stride;
    float mnlr = fminf(d0, d2), mntb = fminf(d1, d3);
    float mxlr = fmaxf(d0, d2), mxtb = fmaxf(d1, d3);
    ctrv = sqrtf((mnlr * mntb) / (mxlr * mxtb));
  }
  long dbase = DELTA_OFF + ((long)b * NT + n) * 4;
  if (!bf) {
    *(float4*)((float*)out + dbase) = make_float4(d0, d1, d2, d3);
  } else {
    ushort4 v; v.x = f2bf(d0); v.y = f2bf(d1); v.z = f2bf(d2); v.w = f2bf(d3);
    *(ushort4*)((unsigned short*)out + dbase) = v;
  }
  stout(out, CTR_OFF + (long)b * NT + n, ctrv, bf);

  // ---- scores + decode ----
  float ct  = ldin(CT, (long)b * NL + nl, bf);
  float sct = 1.0f / (1.0f + expf(-ct));
  float smax = -1.0f; int ci = 0;              // argmax over sqrt-scores, strict >
  for (int c = 0; c < NC; ++c) {
    float v  = scls[tid * 21 + c];
    float sv = 1.0f / (1.0f + expf(-v));
    float s  = sqrtf(sv * sct);
    if (s > smax) { smax = s; ci = c; }
  }
  float r0, r1, r2, r3;
  long rbase = ((long)b * NL + nl) * 4;
  if (!bf) {
    float4 rv = *(const float4*)((const float*)RG + rbase);
    r0 = rv.x; r1 = rv.y; r2 = rv.z; r3 = rv.w;
  } else {
    uint2 rw = *(const uint2*)((const unsigned short*)RG + rbase);
    r0 = __uint_as_float((rw.x & 0xFFFFu) << 16); r1 = __uint_as_float(rw.x & 0xFFFF0000u);
    r2 = __uint_as_float((rw.y & 0xFFFFu) << 16); r3 = __uint_as_float(rw.y & 0xFFFF0000u);
  }
  r0 = fmaxf(r0, 0.f); r1 = fmaxf(r1, 0.f); r2 = fmaxf(r2, 0.f); r3 = fmaxf(r3, 0.f);
  long o = (long)b * NT + n;
  scores[o] = smax;
  *(float4*)(boxesw + o * 4) =
      make_float4(cx - r0 * stride, cy - r1 * stride, cx + r2 * stride, cy + r3 * stride);
  cidw[o] = (float)ci;
}

// ---------- K2: top-1000 (ballot binary-search select + bitonic) + bitmask NMS ----------
// NT == 21 * 1024 exactly: each thread holds 21 inverted-score keys in registers.
__global__ __launch_bounds__(1024)
void k_nms(const float* scores, const float* boxesw, const float* cidw,
           void* out, const int* flagp) {
  const int bf   = *flagp;
  const int b    = blockIdx.x;
  const int tid  = threadIdx.x;
  const int wid  = tid >> 6;
  const int lane = tid & 63;
  const float* sb = scores + (long)b * NT;

  // layout (bytes):
  //   [0,20480)      sbx  (1024 x stride-5 floats)  -- overlays selKeys/red (phase 1)
  //   [20480,36864)  bxs  (1024 x 4 floats)
  //   [36864,40960)  scS
  //   [40960,45056)  cidS
  //   [45056,49152)  areaS
  __shared__ __align__(16) char smem[49152];
  float*              sbx     = (float*)smem;
  unsigned long long* selKeys = (unsigned long long*)smem;   // [1024]
  float*              red     = (float*)smem;                // [16] wave partials
  float*              bxs     = (float*)(smem + 20480);
  float*              scS     = (float*)(smem + 36864);
  float*              cidS    = (float*)(smem + 40960);
  float*              areaS   = (float*)(smem + 45056);
  __shared__ unsigned long long act[16];
  __shared__ unsigned long long keepMask[16];
  __shared__ unsigned wcnt_s[16];
  __shared__ unsigned selCnt;
  __shared__ int      sCurI;
  __shared__ float    sMaxC;

  // load my 21 inverted keys (coalesced, once)
  unsigned inv[21];
#pragma unroll
  for (int k = 0; k < 21; ++k)
    inv[k] = ~__float_as_uint(sb[tid + k * 1024]);

  // --- binary search for V = 1000th smallest inv (no atomics) ---
  unsigned V = 0;
  for (int bit = 31; bit >= 0; --bit) {
    unsigned T = V | (1u << bit);
    unsigned c = 0;
#pragma unroll
    for (int k = 0; k < 21; ++k)
      c += (unsigned)__popcll(__ballot(inv[k] < T));
    if (lane == 0) wcnt_s[wid] = c;
    __syncthreads();
    unsigned tot = 0;
    for (int w = 0; w < 16; ++w) tot += wcnt_s[w];
    if (tot < TOPK) V = T;            // same decision on every thread
    __syncthreads();
  }

  // --- gather: inv < V first (<=999), then ties at V ---
  if (tid == 0) selCnt = 0u;
  __syncthreads();
#pragma unroll
  for (int k = 0; k < 21; ++k)
    if (inv[k] < V) {
      unsigned p = atomicAdd(&selCnt, 1u);
      if (p < 1024u) selKeys[p] = ((unsigned long long)inv[k] << 32) | (unsigned)(tid + k * 1024);
    }
  __syncthreads();
#pragma unroll
  for (int k = 0; k < 21; ++k)
    if (inv[k] == V) {
      unsigned p = atomicAdd(&selCnt, 1u);
      if (p < 1024u) selKeys[p] = ((unsigned long long)inv[k] << 32) | (unsigned)(tid + k * 1024);
    }
  __syncthreads();
  unsigned total = selCnt < 1024u ? selCnt : 1024u;
  if ((unsigned)tid >= total) selKeys[tid] = 0xFFFFFFFFFFFFFFFFull;
  __syncthreads();

  // --- bitonic sort ascending: (inv asc, idx asc) == (score desc, idx asc) ---
  for (unsigned k = 2; k <= 1024; k <<= 1) {
    for (unsigned j = k >> 1; j > 0; j >>= 1) {
      unsigned ixj = (unsigned)tid ^ j;
      if (ixj > (unsigned)tid) {
        unsigned long long a = selKeys[tid], c = selKeys[ixj];
        bool up = ((tid & k) == 0);
        if (up ? (a > c) : (a < c)) { selKeys[tid] = c; selKeys[ixj] = a; }
      }
      __syncthreads();
    }
  }

  // --- gather top boxes/scores/cls ---
  {
    unsigned long long key = selKeys[tid];
    unsigned idx  = (unsigned)key;
    unsigned kinv = (unsigned)(key >> 32);
    scS[tid] = __uint_as_float(~kinv);        // sentinel -> 0.0f
    if (key != 0xFFFFFFFFFFFFFFFFull) {
      long o = (long)b * NT + idx;
      float4 bv = *(const float4*)(boxesw + o * 4);
      bxs[tid*4+0] = bv.x; bxs[tid*4+1] = bv.y; bxs[tid*4+2] = bv.z; bxs[tid*4+3] = bv.w;
      cidS[tid] = cidw[o];
    } else {
      bxs[tid*4+0] = 0.f; bxs[tid*4+1] = 0.f; bxs[tid*4+2] = 0.f; bxs[tid*4+3] = 0.f;
      cidS[tid] = 0.f;
    }
  }
  __syncthreads();   // selKeys dead from here

  // --- max_coord = max(where(valid, bx, 0)) over the 1000 rows ---
  float loc = -INFINITY;
  if (tid < TOPK)
    loc = (scS[tid] > 0.3f)
            ? fmaxf(fmaxf(bxs[tid*4+0], bxs[tid*4+1]), fmaxf(bxs[tid*4+2], bxs[tid*4+3]))
            : 0.0f;
  for (int o = 32; o > 0; o >>= 1) loc = fmaxf(loc, __shfl_down(loc, o));
  if (lane == 0) red[wid] = loc;
  __syncthreads();
  if (tid == 0) {
    float m = red[0];
    for (int w = 1; w < 16; ++w) m = fmaxf(m, red[w]);
    sMaxC = m;
  }
  __syncthreads();

  // --- shifted boxes (stride 5: conflict-free) + areas ---
  float offm = sMaxC + 1.0f;
  if (tid < TOPK) {
    float o4 = cidS[tid] * offm;
    float s0 = bxs[tid*4+0] + o4, s1 = bxs[tid*4+1] + o4;
    float s2 = bxs[tid*4+2] + o4, s3 = bxs[tid*4+3] + o4;
    sbx[tid*5+0] = s0; sbx[tid*5+1] = s1; sbx[tid*5+2] = s2; sbx[tid*5+3] = s3;
    areaS[tid] = (s2 - s0) * (s3 - s1);
  }
  bool valid = (tid < TOPK) && (scS[tid] > 0.3f);
  unsigned long long vb = __ballot(valid);
  if (lane == 0) { act[wid] = vb; keepMask[wid] = 0ull; }
  __syncthreads();

  // --- greedy NMS via active bitmask: <=100 pick-steps ---
  int kept = 0;
  for (;;) {
    if (tid == 0) {
      int nxt = -1;
      for (int w = 0; w < 16; ++w) {
        unsigned long long a = act[w];
        if (a) { nxt = w * 64 + (__ffsll(a) - 1); break; }
      }
      sCurI = nxt;
    }
    __syncthreads();
    int i = sCurI;
    if (i < 0 || kept >= 100) break;
    if (tid == 0) keepMask[i >> 6] |= (1ull << (i & 63));
    float b0 = sbx[i*5+0], b1 = sbx[i*5+1], b2 = sbx[i*5+2], b3 = sbx[i*5+3];
    float ai = areaS[i];
    bool sup = false;
    if (tid < TOPK) {
      float xx1 = fmaxf(b0, sbx[tid*5+0]);
      float yy1 = fmaxf(b1, sbx[tid*5+1]);
      float xx2 = fminf(b2, sbx[tid*5+2]);
      float yy2 = fminf(b3, sbx[tid*5+3]);
      float inter = fmaxf(xx2 - xx1, 0.f) * fmaxf(yy2 - yy1, 0.f);
      float iou = inter / (ai + areaS[tid] - inter);
      sup = !(iou <= 0.5f);                   // NaN suppresses, like the ref
    }
    unsigned long long sm = __ballot(sup);
    if (lane == 0) act[wid] &= ~sm;
    ++kept;
    __syncthreads();
  }
  __syncthreads();

  // --- write dets ---
  if (tid < TOPK) {
    bool kp = (keepMask[tid >> 6] >> (tid & 63)) & 1ull;
    long o = ((long)b * TOPK + tid) * 5;
    float w0 = kp ? bxs[tid*4+0] : 0.f;
    float w1 = kp ? bxs[tid*4+1] : 0.f;
    float w2 = kp ? bxs[tid*4+2] : 0.f;
    float w3 = kp ? bxs[tid*4+3] : 0.f;
    float w4 = kp ? scS[tid]     : 0.f;
    stout(out, o + 0, w0, bf); stout(out, o + 1, w1, bf);
    stout(out, o + 2, w2, bf); stout(out, o + 3, w3, bf);
    stout(out, o + 4, w4, bf);
  }
}

extern "C" void kernel_launch(void* const* d_in, const int* in_sizes, int n_in,
                              void* d_out, int out_size, void* d_ws, size_t ws_size,
                              hipStream_t stream) {
  const void* locs0 = d_in[0];
  const void* locs1 = d_in[1];
  const void* locs2 = d_in[2];
  const void* gt    = d_in[3];

  int ic[3], ir[3], it[3];
  if (n_in >= 13 && in_sizes[5] == 16 * 4096 * 20) {
    ic[0]=4; ic[1]=5; ic[2]=6;  ir[0]=7; ir[1]=8; ir[2]=9;  it[0]=10; it[1]=11; it[2]=12;
  } else {
    ic[0]=4; ic[1]=7; ic[2]=10; ir[0]=5; ir[1]=8; ir[2]=11; it[0]=6;  it[1]=9;  it[2]=12;
  }
  const void* cls0 = d_in[ic[0]]; const void* cls1 = d_in[ic[1]]; const void* cls2 = d_in[ic[2]];
  const void* reg0 = d_in[ir[0]]; const void* reg1 = d_in[ir[1]]; const void* reg2 = d_in[ir[2]];
  const void* ctr0 = d_in[it[0]]; const void* ctr1 = d_in[it[1]]; const void* ctr2 = d_in[it[2]];

  char* ws = (char*)d_ws;
  int*   flag   = (int*)ws;
  float* scores = (float*)(ws + 16);
  float* boxesw = scores + (long)NB * NT;
  float* cidw   = boxesw + (long)NB * NT * 4;

  k_flag<<<1, 1, 0, stream>>>(locs0, flag);
  k_main<<<dim3(NT / 256, NB), 256, 0, stream>>>(locs0, locs1, locs2, gt,
                                                 cls0, cls1, cls2,
                                                 reg0, reg1, reg2,
                                                 ctr0, ctr1, ctr2,
                                                 d_out, scores, boxesw, cidw, flag);
  k_nms<<<NB, 1024, 0, stream>>>(scores, boxesw, cidw, d_out, flag);
}